// Round 1
// baseline (427.171 us; speedup 1.0000x reference)
//
#include <hip/hip_runtime.h>

// OHEM loss, MI355X. B=8, C=19, H=512, W=1024.
// Main path: n_over = count(loss > 0.7) per batch; with this data n_over >> 10000,
// so kept_sum == sum(loss where loss > 0.7) and no sort is needed.
// Fallback (n_over < MIN_KEPT) handled device-side via value-bisection top-k.

#define BB 8
#define CC 19
#define HW (512 * 1024)
#define THRESH 0.7f
#define MIN_KEPT 10000

__device__ __forceinline__ float wave_reduce_f(float v) {
#pragma unroll
    for (int off = 32; off > 0; off >>= 1) v += __shfl_down(v, off, 64);
    return v;
}
__device__ __forceinline__ int wave_reduce_i(int v) {
#pragma unroll
    for (int off = 32; off > 0; off >>= 1) v += __shfl_down(v, off, 64);
    return v;
}

// ---------------- main loss pass ----------------
// grid: (HW/(4*256), B), block: 256. Each thread: 4 consecutive pixels (float4).
__global__ __launch_bounds__(256) void ohem_loss_pass(
    const float* __restrict__ preds, const int* __restrict__ tgts,
    float* __restrict__ sums, int* __restrict__ counts) {
    const int b = blockIdx.y;
    const int q = blockIdx.x * 256 + threadIdx.x;  // quad index within batch

    const float4* p4 = (const float4*)(preds + (size_t)b * CC * HW);
    const int4* t4 = (const int4*)(tgts + (size_t)b * HW);
    const int QHW = HW / 4;

    int4 t = t4[q];

    float4 a[CC];
#pragma unroll
    for (int c = 0; c < CC; ++c) a[c] = p4[(size_t)c * QHW + q];

    // elementwise max over classes
    float4 m = a[0];
#pragma unroll
    for (int c = 1; c < CC; ++c) {
        m.x = fmaxf(m.x, a[c].x);
        m.y = fmaxf(m.y, a[c].y);
        m.z = fmaxf(m.z, a[c].z);
        m.w = fmaxf(m.w, a[c].w);
    }
    // select logit[target] per pixel (predicated, no dynamic reg index)
    float4 tv = a[0];
#pragma unroll
    for (int c = 1; c < CC; ++c) {
        tv.x = (t.x == c) ? a[c].x : tv.x;
        tv.y = (t.y == c) ? a[c].y : tv.y;
        tv.z = (t.z == c) ? a[c].z : tv.z;
        tv.w = (t.w == c) ? a[c].w : tv.w;
    }
    // sum of exp(a - m)
    float4 s = {0.f, 0.f, 0.f, 0.f};
#pragma unroll
    for (int c = 0; c < CC; ++c) {
        s.x += __expf(a[c].x - m.x);
        s.y += __expf(a[c].y - m.y);
        s.z += __expf(a[c].z - m.z);
        s.w += __expf(a[c].w - m.w);
    }
    float l0 = m.x - tv.x + __logf(s.x);
    float l1 = m.y - tv.y + __logf(s.y);
    float l2 = m.z - tv.z + __logf(s.z);
    float l3 = m.w - tv.w + __logf(s.w);

    float sloc = 0.f;
    int cloc = 0;
    if (l0 > THRESH) { sloc += l0; ++cloc; }
    if (l1 > THRESH) { sloc += l1; ++cloc; }
    if (l2 > THRESH) { sloc += l2; ++cloc; }
    if (l3 > THRESH) { sloc += l3; ++cloc; }

    // block reduce: 4 waves
    __shared__ float sbuf[4];
    __shared__ int cbuf[4];
    float wsum = wave_reduce_f(sloc);
    int wcnt = wave_reduce_i(cloc);
    const int wid = threadIdx.x >> 6;
    const int lane = threadIdx.x & 63;
    if (lane == 0) { sbuf[wid] = wsum; cbuf[wid] = wcnt; }
    __syncthreads();
    if (threadIdx.x == 0) {
        float st = sbuf[0] + sbuf[1] + sbuf[2] + sbuf[3];
        int ct = cbuf[0] + cbuf[1] + cbuf[2] + cbuf[3];
        atomicAdd(&sums[b], st);
        atomicAdd(&counts[b], ct);
    }
}

// ---------------- finalize ----------------
__device__ float pixel_loss(const float* __restrict__ preds,
                            const int* __restrict__ tgts, int b, int i) {
    const float* p = preds + (size_t)b * CC * HW + i;
    const int t = tgts[(size_t)b * HW + i];
    float m = -1e30f, tv = 0.f;
#pragma unroll
    for (int c = 0; c < CC; ++c) {
        float v = p[(size_t)c * HW];
        m = fmaxf(m, v);
        tv = (c == t) ? v : tv;
    }
    float s = 0.f;
#pragma unroll
    for (int c = 0; c < CC; ++c) s += __expf(p[(size_t)c * HW] - m);
    return m - tv + __logf(s);
}

__device__ int block_reduce_int(int v, int* buf) {
    v = wave_reduce_i(v);
    const int wid = threadIdx.x >> 6, lane = threadIdx.x & 63;
    __syncthreads();
    if (lane == 0) buf[wid] = v;
    __syncthreads();
    return buf[0] + buf[1] + buf[2] + buf[3];
}
__device__ float block_reduce_f(float v, float* buf) {
    v = wave_reduce_f(v);
    const int wid = threadIdx.x >> 6, lane = threadIdx.x & 63;
    __syncthreads();
    if (lane == 0) buf[wid] = v;
    __syncthreads();
    return buf[0] + buf[1] + buf[2] + buf[3];
}

// single block, 256 threads
__global__ __launch_bounds__(256) void ohem_finalize(
    const float* __restrict__ preds, const int* __restrict__ tgts,
    const float* __restrict__ sums, const int* __restrict__ counts,
    float* __restrict__ out) {
    __shared__ int ibuf[4];
    __shared__ float fbuf[4];

    float total = 0.f;
    for (int b = 0; b < BB; ++b) {
        const int cnt = counts[b];
        const float sm = sums[b];
        float mean;
        if (cnt >= MIN_KEPT) {
            // top-n_over == exactly the losses > THRESH
            mean = sm / (float)cnt;
        } else {
            // fallback: top-MIN_KEPT via value bisection (exact enough; never
            // triggered with this data distribution, resolved on-device)
            float lo = 0.f, hi = 88.f;
            for (int it = 0; it < 40; ++it) {
                const float mid = 0.5f * (lo + hi);
                int c = 0;
                for (int i = threadIdx.x; i < HW; i += 256)
                    c += (pixel_loss(preds, tgts, b, i) > mid) ? 1 : 0;
                c = block_reduce_int(c, ibuf);
                if (c >= MIN_KEPT) lo = mid; else hi = mid;
                __syncthreads();
            }
            float ssum = 0.f;
            int sc = 0;
            for (int i = threadIdx.x; i < HW; i += 256) {
                const float l = pixel_loss(preds, tgts, b, i);
                if (l > lo) { ssum += l; ++sc; }
            }
            ssum = block_reduce_f(ssum, fbuf);
            sc = block_reduce_int(sc, ibuf);
            const float kept = ssum + (float)(MIN_KEPT - sc) * lo;
            mean = kept / (float)MIN_KEPT;
        }
        total += mean;
    }
    if (threadIdx.x == 0) out[0] = total / (float)BB;
}

extern "C" void kernel_launch(void* const* d_in, const int* in_sizes, int n_in,
                              void* d_out, int out_size, void* d_ws, size_t ws_size,
                              hipStream_t stream) {
    const float* preds = (const float*)d_in[0];
    const int* tgts = (const int*)d_in[1];
    float* out = (float*)d_out;

    float* sums = (float*)d_ws;                    // 8 floats
    int* counts = (int*)((char*)d_ws + 64);        // 8 ints

    hipMemsetAsync(d_ws, 0, 128, stream);

    dim3 grid(HW / (4 * 256), BB);
    ohem_loss_pass<<<grid, 256, 0, stream>>>(preds, tgts, sums, counts);
    ohem_finalize<<<1, 256, 0, stream>>>(preds, tgts, sums, counts, out);
}